// Round 1
// baseline (245.027 us; speedup 1.0000x reference)
//
#include <hip/hip_runtime.h>

#define QF   64
#define GG   120
#define HID  128
#define NACT 20
#define BTOT 2048   // B*T = 32*64

// ---- workspace layout (bytes) ----
#define WEFF_OFF  0u               // 120*64*128 f32 = 3,932,160 B
#define M_OFF     3932160u         // 120*2048 f32   =   983,040 B
#define MISC_OFF  4915200u         // bmean[128], wmean[128], cb  (1088 B reserved)
#define GMAP_OFF  4916288u         // 120*120 i32 = 57,600 B
#define FPINV_OFF 4973888u         // 120*64  i32 = 30,720 B
#define UBYC_OFF  5004608u         // 20*6    i32 =    480 B

__device__ __forceinline__ void idx_to_perm(int i, int p[5]) {
    int avail[5] = {0, 1, 2, 3, 4};
    const int f[4] = {24, 6, 2, 1};
    for (int k = 0; k < 4; ++k) {
        int d = i / f[k]; i %= f[k];
        p[k] = avail[d];
        for (int j = d; j < 4 - k; ++j) avail[j] = avail[j + 1];
    }
    p[4] = avail[0];
}

__device__ __forceinline__ int perm_to_idx(const int p[5]) {
    const int f[4] = {24, 6, 2, 1};
    int idx = 0;
    for (int k = 0; k < 4; ++k) {
        int c = 0;
        for (int j = k + 1; j < 5; ++j) c += (p[j] < p[k]) ? 1 : 0;
        idx += c * f[k];
    }
    return idx;
}

// Build gmap (120x120), fpinv (120x64), ubycoset (20x6) on device.
__global__ void build_tables(int* __restrict__ gmap, int* __restrict__ fpinv,
                             int* __restrict__ ubycoset) {
    __shared__ int perms[GG][5];
    __shared__ int invp[GG];
    int t = threadIdx.x;
    if (t < GG) {
        int p[5]; idx_to_perm(t, p);
        for (int k = 0; k < 5; ++k) perms[t][k] = p[k];
        int q[5];
        for (int k = 0; k < 5; ++k) q[p[k]] = k;   // inverse permutation
        invp[t] = perm_to_idx(q);
    }
    __syncthreads();
    if (t < GG) {
        // fpinv[t][r]: q bit k (weight 2^(4-k)) = r bit at weight 2^(4-p[k]); top bit kept
        for (int r = 0; r < QF; ++r) {
            int v = r & 32;
            for (int k = 0; k < 5; ++k) {
                int bit = (r >> (4 - perms[t][k])) & 1;
                v |= bit << (4 - k);
            }
            fpinv[t * QF + r] = v;
        }
        // gmap row u=t: Hm[u][p] = pidx(perm_u o perm_{inv[p]}); gmap[u][Hm]=p
        for (int p = 0; p < GG; ++p) {
            int j = invp[p];
            int comp[5];
            for (int mM = 0; mM < 5; ++mM) comp[mM] = perms[t][perms[j][mM]];
            int h = perm_to_idx(comp);
            gmap[t * GG + h] = p;
        }
    }
    __syncthreads();
    if (t == 0) {
        int cnt[NACT];
        for (int a = 0; a < NACT; ++a) cnt[a] = 0;
        for (int p = 0; p < GG; ++p) {
            int a0 = perms[p][0], a1 = perms[p][1];
            int a = a0 * 4 + (a1 > a0 ? a1 - 1 : a1);
            ubycoset[a * 6 + cnt[a]++] = p;
        }
    }
}

// bmean[h], wmean[h] (= mean_n Wout[h][n]), cb (= mean(bout))
__global__ void build_misc(const float* __restrict__ eq_bias,
                           const float* __restrict__ Wout,
                           const float* __restrict__ bout,
                           float* __restrict__ misc) {
    int h = threadIdx.x;   // 128 threads
    float s = 0.f;
    for (int g = 0; g < GG; ++g) s += eq_bias[g * HID + h];
    misc[h] = s * (1.f / GG);
    float w = 0.f;
    for (int n = 0; n < NACT; ++n) w += Wout[h * NACT + n];
    misc[HID + h] = w * (1.f / NACT);
    if (h == 0) {
        float c = 0.f;
        for (int n = 0; n < NACT; ++n) c += bout[n];
        misc[2 * HID] = c * (1.f / NACT);
    }
}

// Weff[u][r][h] = (1/120) sum_p eqw[gmap[u][p]][fpinv[p][r]][h]
__global__ void build_weff(const float* __restrict__ eqw,
                           const int* __restrict__ gmap,
                           const int* __restrict__ fpinv,
                           float* __restrict__ weff) {
    int h = threadIdx.x;                 // 128
    int blk = blockIdx.x;                // u*64 + r
    int u = blk >> 6, r = blk & 63;
    float acc = 0.f;
    for (int p = 0; p < GG; ++p) {
        int g = gmap[u * GG + p];
        int q = fpinv[p * QF + r];
        acc += eqw[(g * QF + q) * HID + h];
    }
    weff[(u * QF + r) * HID + h] = acc * (1.f / GG);
}

// Fused per-u MLP: e=relu(x@Weff[u]+bmean); h2=relu(e@W1+b1); m=h2.wmean
__global__ __launch_bounds__(256)
void mlp_fused(const float* __restrict__ x,     // [2048][64]
               const float* __restrict__ weff,  // [120][64][128]
               const float* __restrict__ W1,    // [128][128]
               const float* __restrict__ b1,    // [128]
               const float* __restrict__ misc,  // bmean[128], wmean[128], cb
               float* __restrict__ m) {         // [120][2048]
    __shared__ float xs[64][QF + 1];     // 64x65
    __shared__ float es[64][HID + 5];    // 64x133 (stride 133: 4 distinct banks over tr)
    int u = blockIdx.y;
    int tile = blockIdx.x;               // 0..31
    int tid = threadIdx.x;
    int tc = tid & 15, tr = tid >> 4;

    // load x tile (64 rows x 64 cols)
    const float* xblk = x + tile * 64 * QF;
    for (int i = tid; i < 64 * 16; i += 256) {
        int row = i >> 4, c4 = (i & 15) * 4;
        float4 v = *reinterpret_cast<const float4*>(xblk + row * QF + c4);
        xs[row][c4 + 0] = v.x; xs[row][c4 + 1] = v.y;
        xs[row][c4 + 2] = v.z; xs[row][c4 + 3] = v.w;
    }
    __syncthreads();

    // stage A: E(64x128) = xs(64x64) @ weff[u](64x128)
    const float* wu = weff + u * QF * HID;
    float acc[4][8];
#pragma unroll
    for (int i = 0; i < 4; ++i)
#pragma unroll
        for (int j = 0; j < 8; ++j) acc[i][j] = 0.f;

    for (int q = 0; q < QF; ++q) {
        float4 w0 = *reinterpret_cast<const float4*>(wu + q * HID + tc * 8);
        float4 w1v = *reinterpret_cast<const float4*>(wu + q * HID + tc * 8 + 4);
        float xv[4];
#pragma unroll
        for (int i = 0; i < 4; ++i) xv[i] = xs[tr * 4 + i][q];
#pragma unroll
        for (int i = 0; i < 4; ++i) {
            acc[i][0] += xv[i] * w0.x; acc[i][1] += xv[i] * w0.y;
            acc[i][2] += xv[i] * w0.z; acc[i][3] += xv[i] * w0.w;
            acc[i][4] += xv[i] * w1v.x; acc[i][5] += xv[i] * w1v.y;
            acc[i][6] += xv[i] * w1v.z; acc[i][7] += xv[i] * w1v.w;
        }
    }
    // + bmean, relu -> es
#pragma unroll
    for (int j = 0; j < 8; ++j) {
        float bm = misc[tc * 8 + j];
#pragma unroll
        for (int i = 0; i < 4; ++i) {
            float v = acc[i][j] + bm;
            es[tr * 4 + i][tc * 8 + j] = v > 0.f ? v : 0.f;
        }
    }
    __syncthreads();

    // stage B: H2(64x128) = es(64x128) @ W1(128x128)
    float acc2[4][8];
#pragma unroll
    for (int i = 0; i < 4; ++i)
#pragma unroll
        for (int j = 0; j < 8; ++j) acc2[i][j] = 0.f;

    for (int k = 0; k < HID; ++k) {
        float4 w0 = *reinterpret_cast<const float4*>(W1 + k * HID + tc * 8);
        float4 w1v = *reinterpret_cast<const float4*>(W1 + k * HID + tc * 8 + 4);
        float ev[4];
#pragma unroll
        for (int i = 0; i < 4; ++i) ev[i] = es[tr * 4 + i][k];
#pragma unroll
        for (int i = 0; i < 4; ++i) {
            acc2[i][0] += ev[i] * w0.x; acc2[i][1] += ev[i] * w0.y;
            acc2[i][2] += ev[i] * w0.z; acc2[i][3] += ev[i] * w0.w;
            acc2[i][4] += ev[i] * w1v.x; acc2[i][5] += ev[i] * w1v.y;
            acc2[i][6] += ev[i] * w1v.z; acc2[i][7] += ev[i] * w1v.w;
        }
    }

    // + b1, relu, dot with wmean; reduce over the 16 tc lanes
    float ms[4] = {0.f, 0.f, 0.f, 0.f};
#pragma unroll
    for (int j = 0; j < 8; ++j) {
        float bb = b1[tc * 8 + j];
        float wm = misc[HID + tc * 8 + j];
#pragma unroll
        for (int i = 0; i < 4; ++i) {
            float v = acc2[i][j] + bb;
            v = v > 0.f ? v : 0.f;
            ms[i] += v * wm;
        }
    }
#pragma unroll
    for (int off = 1; off < 16; off <<= 1) {
#pragma unroll
        for (int i = 0; i < 4; ++i) ms[i] += __shfl_xor(ms[i], off);
    }
    if (tc == 0) {
        int rowbase = tile * 64 + tr * 4;
#pragma unroll
        for (int i = 0; i < 4; ++i) m[u * BTOT + rowbase + i] = ms[i];
    }
}

// y[bt][a] = (1/6) sum_{u in coset a} m[u][bt] + cb
__global__ void reduce_out(const float* __restrict__ m,
                           const int* __restrict__ ubycoset,
                           const float* __restrict__ misc,
                           float* __restrict__ out) {
    int idx = blockIdx.x * 256 + threadIdx.x;   // bt*20 + a
    if (idx >= BTOT * NACT) return;
    int bt = idx / NACT, a = idx % NACT;
    float s = 0.f;
#pragma unroll
    for (int j = 0; j < 6; ++j) s += m[ubycoset[a * 6 + j] * BTOT + bt];
    out[idx] = s * (1.f / 6.f) + misc[2 * HID];
}

extern "C" void kernel_launch(void* const* d_in, const int* in_sizes, int n_in,
                              void* d_out, int out_size, void* d_ws, size_t ws_size,
                              hipStream_t stream) {
    const float* x       = (const float*)d_in[0];   // 32*64*64
    const float* eqw     = (const float*)d_in[1];   // 120*64*128
    const float* eq_bias = (const float*)d_in[2];   // 120*128
    const float* W1      = (const float*)d_in[3];   // 128*128
    const float* b1      = (const float*)d_in[4];   // 128
    const float* Wout    = (const float*)d_in[5];   // 128*20
    const float* bout    = (const float*)d_in[6];   // 20
    float* out           = (float*)d_out;           // 2048*20

    char* ws = (char*)d_ws;
    float* weff    = (float*)(ws + WEFF_OFF);
    float* mbuf    = (float*)(ws + M_OFF);
    float* misc    = (float*)(ws + MISC_OFF);
    int* gmap      = (int*)(ws + GMAP_OFF);
    int* fpinv     = (int*)(ws + FPINV_OFF);
    int* ubycoset  = (int*)(ws + UBYC_OFF);

    hipLaunchKernelGGL(build_tables, dim3(1), dim3(128), 0, stream,
                       gmap, fpinv, ubycoset);
    hipLaunchKernelGGL(build_misc, dim3(1), dim3(128), 0, stream,
                       eq_bias, Wout, bout, misc);
    hipLaunchKernelGGL(build_weff, dim3(GG * QF), dim3(HID), 0, stream,
                       eqw, gmap, fpinv, weff);
    hipLaunchKernelGGL(mlp_fused, dim3(32, GG), dim3(256), 0, stream,
                       x, weff, W1, b1, misc, mbuf);
    hipLaunchKernelGGL(reduce_out, dim3((BTOT * NACT + 255) / 256), dim3(256), 0, stream,
                       mbuf, ubycoset, misc, out);
}